// Round 4
// baseline (44.862 us; speedup 1.0000x reference)
//
#include <hip/hip_runtime.h>
#include <math.h>

#define NROWS 65536
#define DDIM 512
#define NUM_CLASSES 1000
#define ROWS_PER_WAVE 8
#define NBLOCKS (NROWS / ROWS_PER_WAVE / 4)   // 2048 blocks * 4 waves * 8 rows

// --- kernel 1: zero the 1000 class bins (single block) ---
__global__ __launch_bounds__(256) void CenterLoss_zero_ws(float* __restrict__ ws) {
    for (int i = threadIdx.x; i < NUM_CLASSES; i += 256) ws[i] = 0.0f;
}

__device__ inline float sqdiff4(float4 a, float4 b) {
    float dx = a.x - b.x, dy = a.y - b.y, dz = a.z - b.z, dw = a.w - b.w;
    return fmaf(dx, dx, fmaf(dy, dy, fmaf(dz, dz, dw * dw)));
}

// --- kernel 2: 8 rows per wave (2 chunks of 4), 2048 blocks ---
// No fences, no flags: inter-kernel ordering comes from the stream/launch
// boundary (R2 lesson: per-block device-scope fences = L2 flush storm).
__global__ __launch_bounds__(256, 6) void CenterLoss_accum(
    const float* __restrict__ x,
    const int* __restrict__ labels,
    const float* __restrict__ centers,
    float* __restrict__ ws)
{
    const int lane = threadIdx.x & 63;
    const int wid  = (blockIdx.x << 2) + (threadIdx.x >> 6);
    const int row0 = wid * ROWS_PER_WAVE;

#pragma unroll
    for (int half = 0; half < 2; ++half) {
        const int r = row0 + half * 4;

        // 4 consecutive labels: wave-uniform -> one s_load_dwordx4
        const int l0 = labels[r + 0];
        const int l1 = labels[r + 1];
        const int l2 = labels[r + 2];
        const int l3 = labels[r + 3];

        const float4* __restrict__ x0 = (const float4*)(x + (size_t)(r + 0) * DDIM);
        const float4* __restrict__ x1 = (const float4*)(x + (size_t)(r + 1) * DDIM);
        const float4* __restrict__ x2 = (const float4*)(x + (size_t)(r + 2) * DDIM);
        const float4* __restrict__ x3 = (const float4*)(x + (size_t)(r + 3) * DDIM);
        const float4* __restrict__ c0 = (const float4*)(centers + (size_t)l0 * DDIM);
        const float4* __restrict__ c1 = (const float4*)(centers + (size_t)l1 * DDIM);
        const float4* __restrict__ c2 = (const float4*)(centers + (size_t)l2 * DDIM);
        const float4* __restrict__ c3 = (const float4*)(centers + (size_t)l3 * DDIM);

        // 16 independent float4 loads (8 KB/wave in flight)
        const float4 xa0 = x0[lane], xb0 = x0[lane + 64];
        const float4 xa1 = x1[lane], xb1 = x1[lane + 64];
        const float4 xa2 = x2[lane], xb2 = x2[lane + 64];
        const float4 xa3 = x3[lane], xb3 = x3[lane + 64];
        const float4 ca0 = c0[lane], cb0 = c0[lane + 64];
        const float4 ca1 = c1[lane], cb1 = c1[lane + 64];
        const float4 ca2 = c2[lane], cb2 = c2[lane + 64];
        const float4 ca3 = c3[lane], cb3 = c3[lane + 64];

        float a0 = sqdiff4(xa0, ca0) + sqdiff4(xb0, cb0);
        float a1 = sqdiff4(xa1, ca1) + sqdiff4(xb1, cb1);
        float a2 = sqdiff4(xa2, ca2) + sqdiff4(xb2, cb2);
        float a3 = sqdiff4(xa3, ca3) + sqdiff4(xb3, cb3);

        // 4 interleaved 64-lane butterflies (ILP 4)
#pragma unroll
        for (int off = 32; off > 0; off >>= 1) {
            a0 += __shfl_xor(a0, off, 64);
            a1 += __shfl_xor(a1, off, 64);
            a2 += __shfl_xor(a2, off, 64);
            a3 += __shfl_xor(a3, off, 64);
        }

        // one atomic instruction, 4 active lanes, 4 (generally distinct) bins
        const float av = (lane == 0) ? a0 : (lane == 1) ? a1 : (lane == 2) ? a2 : a3;
        const int   ab = (lane == 0) ? l0 : (lane == 1) ? l1 : (lane == 2) ? l2 : l3;
        if (lane < 4) atomicAdd(&ws[ab], av);
    }
}

// --- kernel 3: sqrt bins, sum, scale (single block, 256 threads) ---
__global__ __launch_bounds__(256) void CenterLoss_finalize(
    const float* __restrict__ ws, float* __restrict__ out)
{
    const int t = threadIdx.x;
    const int lane = t & 63;

    float s = 0.0f;
    if (t < NUM_CLASSES / 4) {               // 250 threads, 1000 = 250 float4
        float4 v = reinterpret_cast<const float4*>(ws)[t];
        s = sqrtf(v.x) + sqrtf(v.y) + sqrtf(v.z) + sqrtf(v.w);
    }
#pragma unroll
    for (int off = 32; off > 0; off >>= 1)
        s += __shfl_xor(s, off, 64);

    __shared__ float partial[4];
    if (lane == 0) partial[t >> 6] = s;
    __syncthreads();
    if (t == 0)
        out[0] = (partial[0] + partial[1] + partial[2] + partial[3])
                 / (float)NUM_CLASSES;
}

extern "C" void kernel_launch(void* const* d_in, const int* in_sizes, int n_in,
                              void* d_out, int out_size, void* d_ws, size_t ws_size,
                              hipStream_t stream) {
    const float* x       = (const float*)d_in[0];
    const int*   labels  = (const int*)d_in[1];
    const float* centers = (const float*)d_in[2];
    float* out = (float*)d_out;
    float* ws  = (float*)d_ws;

    CenterLoss_zero_ws<<<1, 256, 0, stream>>>(ws);
    CenterLoss_accum<<<NBLOCKS, 256, 0, stream>>>(x, labels, centers, ws);
    CenterLoss_finalize<<<1, 256, 0, stream>>>(ws, out);
}